// Round 7
// baseline (946.103 us; speedup 1.0000x reference)
//
#include <hip/hip_runtime.h>
#include <hip/hip_bf16.h>
#include <math.h>

typedef __hip_bfloat16 bf16;
typedef __attribute__((ext_vector_type(8))) short short8;
typedef __attribute__((ext_vector_type(4))) float floatx4;

static constexpr int TOK = 32768;
static constexpr int CDIM = 384;
static constexpr int HID = 1536;

__device__ __forceinline__ bf16 f2bf(float v) { return __float2bfloat16(v); }

__device__ __forceinline__ unsigned short bf_bits(float a) {
  bf16 h = __float2bfloat16(a);
  unsigned short u;
  __builtin_memcpy(&u, &h, 2);
  return u;
}
__device__ __forceinline__ unsigned pack2(float a, float b) {
  return (unsigned)bf_bits(a) | ((unsigned)bf_bits(b) << 16);
}

// ---------------- weight fp32 -> bf16 transposed ----------------
__global__ void k_convt(const float* __restrict__ src, bf16* __restrict__ dst,
                        int Kd, int Nd) {
  int tid = blockIdx.x * 256 + threadIdx.x;
  if (tid >= Kd * Nd) return;
  int k = tid / Nd, n = tid - k * Nd;
  dst[(size_t)n * Kd + k] = f2bf(src[tid]);
}

// ---------------- LN1 + shift + window partition (4 tokens/block) -----------
__global__ __launch_bounds__(256) void k_ln1(const float* __restrict__ x,
                                             const float* __restrict__ g,
                                             const float* __restrict__ b,
                                             bf16* __restrict__ out) {
  int wt = blockIdx.x * 4 + (threadIdx.x >> 6);
  int lane = threadIdx.x & 63;
  int win = wt >> 6, ntok = wt & 63;
  int bimg = win >> 4, wi = win & 15;
  int sh = (((wi >> 2) << 3) + (ntok >> 3) + 4) & 31;
  int sw = (((wi & 3) << 3) + (ntok & 7) + 4) & 31;
  const float* xr = x + ((size_t)bimg * 1024 + sh * 32 + sw) * CDIM;
  float v[6]; float s = 0.f, ss = 0.f;
#pragma unroll
  for (int j = 0; j < 6; ++j) {
    float t = xr[j * 64 + lane];
    v[j] = t; s += t; ss += t * t;
  }
#pragma unroll
  for (int off = 32; off > 0; off >>= 1) {
    s += __shfl_xor(s, off, 64);
    ss += __shfl_xor(ss, off, 64);
  }
  float mu = s * (1.f / 384.f);
  float var = ss * (1.f / 384.f) - mu * mu;
  float rs = rsqrtf(var + 1e-5f);
  bf16* orow = out + (size_t)wt * CDIM;
#pragma unroll
  for (int j = 0; j < 6; ++j) {
    int c = j * 64 + lane;
    orow[c] = f2bf((v[j] - mu) * rs * g[c] + b[c]);
  }
}

// ---------------- LN2 (normal token order, 4 tokens/block) ------------------
__global__ __launch_bounds__(256) void k_ln2(const float* __restrict__ x1,
                                             const float* __restrict__ g,
                                             const float* __restrict__ b,
                                             bf16* __restrict__ out) {
  int t = blockIdx.x * 4 + (threadIdx.x >> 6);
  int lane = threadIdx.x & 63;
  const float* xr = x1 + (size_t)t * CDIM;
  float v[6]; float s = 0.f, ss = 0.f;
#pragma unroll
  for (int j = 0; j < 6; ++j) {
    float q = xr[j * 64 + lane];
    v[j] = q; s += q; ss += q * q;
  }
#pragma unroll
  for (int off = 32; off > 0; off >>= 1) {
    s += __shfl_xor(s, off, 64);
    ss += __shfl_xor(ss, off, 64);
  }
  float mu = s * (1.f / 384.f);
  float var = ss * (1.f / 384.f) - mu * mu;
  float rs = rsqrtf(var + 1e-5f);
  bf16* orow = out + (size_t)t * CDIM;
#pragma unroll
  for (int j = 0; j < 6; ++j) {
    int c = j * 64 + lane;
    orow[c] = f2bf((v[j] - mu) * rs * g[c] + b[c]);
  }
}

// ==== GEMM: 128xTN tile, BK=64, XCD swizzle, register-staged pipeline =======
// Pipeline: global->VGPR loads for step k+1 issued right after step k's RAW
// barrier, consumed by ds_write at step k+1's front — a full MFMA phase of
// latency overlap per wave (vs global_load_lds which exposed the whole HBM
// latency at each barrier). LDS single-buffered; k-chunk XOR swizzle kept
// (R6 measured SQ_LDS_BANK_CONFLICT == 0).
// TN=128: 4 waves in 2x2, each 64x64. TN=64: 4 waves stacked on M, each 32x64.
template <int K, int EPI, int NT, int TN>
__global__ __launch_bounds__(256) void k_gemm(const bf16* __restrict__ A,
                                              const bf16* __restrict__ Bt,
                                              const float* __restrict__ bias,
                                              const float* __restrict__ extra,
                                              void* __restrict__ outp) {
  constexpr int NB = (TN == 128) ? 4 : 2;   // B-staging chunks per thread
  constexpr int MT = (TN == 128) ? 4 : 2;   // 16-row frags per wave
  __shared__ __attribute__((aligned(16))) char pool[16384 + NB * 4096];
  bf16* As = (bf16*)pool;                   // [128][64]
  bf16* Bs = (bf16*)(pool + 16384);         // [TN][64]

  const int tid = threadIdx.x;
  const int wv = tid >> 6, lane = tid & 63;

  const int flat = blockIdx.x;
  const int xcd = flat & 7;
  const int idx = flat >> 3;
  const int rpx = (gridDim.x >> 3) / NT;
  const int cb = idx % NT;
  const int rb = idx / NT;
  const int mblk = (xcd * rpx + rb) * 128, nblk = cb * TN;

  const int srow = lane >> 3;
  const int scol8 = (lane & 7) ^ srow;
  const bf16* gaw = A + (size_t)(mblk + wv * 32 + srow) * K + scol8 * 8;
  const bf16* gbw = Bt + (size_t)(nblk + wv * (NB * 8) + srow) * K + scol8 * 8;

  const int wrow = (TN == 128) ? (wv >> 1) * 64 : wv * 32;
  const int wcol = (TN == 128) ? (wv & 1) * 64 : 0;
  const int mr = lane & 15, q = lane >> 4;
  const bf16* faRow = As + (wrow + mr) * 64;
  const bf16* fbRow = Bs + (wcol + mr) * 64;
  const int sw0 = (q ^ (mr & 7)) * 8;
  const int sw4 = ((q + 4) ^ (mr & 7)) * 8;

  floatx4 acc[MT][4];
#pragma unroll
  for (int i = 0; i < MT; ++i)
#pragma unroll
    for (int j = 0; j < 4; ++j) acc[i][j] = floatx4{0.f, 0.f, 0.f, 0.f};

  uint4 ra[4], rb_[NB];
#pragma unroll
  for (int c = 0; c < 4; ++c) ra[c] = *(const uint4*)(gaw + c * 8 * K);
#pragma unroll
  for (int c = 0; c < NB; ++c) rb_[c] = *(const uint4*)(gbw + c * 8 * K);

  for (int k0 = 0; k0 < K; k0 += 64) {
    __syncthreads();  // WAR: all waves done reading LDS
    // ds_write staged regs (compiler inserts the vmcnt wait here; loads were
    // issued a full MFMA-phase ago)
#pragma unroll
    for (int c = 0; c < 4; ++c)
      *(uint4*)(As + wv * 2048 + c * 512 + lane * 8) = ra[c];
#pragma unroll
    for (int c = 0; c < NB; ++c)
      *(uint4*)(Bs + wv * (NB * 512) + c * 512 + lane * 8) = rb_[c];
    __syncthreads();  // RAW: writes visible
    if (k0 + 64 < K) {
#pragma unroll
      for (int c = 0; c < 4; ++c) ra[c] = *(const uint4*)(gaw + k0 + 64 + c * 8 * K);
#pragma unroll
      for (int c = 0; c < NB; ++c) rb_[c] = *(const uint4*)(gbw + k0 + 64 + c * 8 * K);
    }
    {
      short8 a[MT], b[4];
#pragma unroll
      for (int mt = 0; mt < MT; ++mt) a[mt] = *(const short8*)(faRow + mt * 1024 + sw0);
#pragma unroll
      for (int nt = 0; nt < 4; ++nt) b[nt] = *(const short8*)(fbRow + nt * 1024 + sw0);
#pragma unroll
      for (int mt = 0; mt < MT; ++mt)
#pragma unroll
        for (int nt = 0; nt < 4; ++nt)
          acc[mt][nt] = __builtin_amdgcn_mfma_f32_16x16x32_bf16(a[mt], b[nt], acc[mt][nt], 0, 0, 0);
    }
    {
      short8 a[MT], b[4];
#pragma unroll
      for (int mt = 0; mt < MT; ++mt) a[mt] = *(const short8*)(faRow + mt * 1024 + sw4);
#pragma unroll
      for (int nt = 0; nt < 4; ++nt) b[nt] = *(const short8*)(fbRow + nt * 1024 + sw4);
#pragma unroll
      for (int mt = 0; mt < MT; ++mt)
#pragma unroll
        for (int nt = 0; nt < 4; ++nt)
          acc[mt][nt] = __builtin_amdgcn_mfma_f32_16x16x32_bf16(a[mt], b[nt], acc[mt][nt], 0, 0, 0);
    }
  }

  // epilogue: staging LDS dead -> alias per-wave transpose buffers
  __syncthreads();
  float* epsw = (float*)pool + wv * (16 * 68);  // 4 x 4352B = 17408 <= pool
  const int rr = lane >> 2, c0 = (lane & 3) * 16;
#pragma unroll
  for (int mt = 0; mt < MT; ++mt) {
#pragma unroll
    for (int nt = 0; nt < 4; ++nt)
#pragma unroll
      for (int r = 0; r < 4; ++r)
        epsw[(q * 4 + r) * 68 + nt * 16 + mr] = acc[mt][nt][r];
    float v[16];
#pragma unroll
    for (int j = 0; j < 4; ++j) {
      float4 t = *(const float4*)&epsw[rr * 68 + c0 + j * 4];
      v[j * 4 + 0] = t.x; v[j * 4 + 1] = t.y; v[j * 4 + 2] = t.z; v[j * 4 + 3] = t.w;
    }
    const int grow = mblk + wrow + mt * 16 + rr;
    const int gcol = nblk + wcol + c0;

    if constexpr (EPI == 0) {
      int win = grow >> 6, ntok = grow & 63;
      int s = gcol / 384;
      int rem = gcol - s * 384;
      int h = rem >> 5, d0 = rem & 31;
      bf16* op = (bf16*)outp + (((size_t)s * 512 + win) * 12 + h) * 2048 + ntok * 32 + d0;
      uint4 pk;
      float bv[16];
#pragma unroll
      for (int j = 0; j < 16; ++j) bv[j] = v[j] + bias[gcol + j];
      pk.x = pack2(bv[0], bv[1]); pk.y = pack2(bv[2], bv[3]);
      pk.z = pack2(bv[4], bv[5]); pk.w = pack2(bv[6], bv[7]);
      *(uint4*)op = pk;
      pk.x = pack2(bv[8], bv[9]); pk.y = pack2(bv[10], bv[11]);
      pk.z = pack2(bv[12], bv[13]); pk.w = pack2(bv[14], bv[15]);
      *(uint4*)(op + 8) = pk;
    } else if constexpr (EPI == 1) {
      int win = grow >> 6, ntok = grow & 63;
      int bimg = win >> 4, wi = win & 15;
      int hh = (((wi >> 2) << 3) + (ntok >> 3) + 4) & 31;
      int ww = (((wi & 3) << 3) + (ntok & 7) + 4) & 31;
      size_t t = (size_t)bimg * 1024 + hh * 32 + ww;
      float* op = (float*)outp + t * CDIM + gcol;
      const float* xr = extra + t * CDIM + gcol;
#pragma unroll
      for (int j = 0; j < 4; ++j) {
        float4 xv = *(const float4*)(xr + j * 4);
        float4 ov;
        ov.x = xv.x + v[j * 4 + 0] + bias[gcol + j * 4 + 0];
        ov.y = xv.y + v[j * 4 + 1] + bias[gcol + j * 4 + 1];
        ov.z = xv.z + v[j * 4 + 2] + bias[gcol + j * 4 + 2];
        ov.w = xv.w + v[j * 4 + 3] + bias[gcol + j * 4 + 3];
        *(float4*)(op + j * 4) = ov;
      }
    } else if constexpr (EPI == 2) {
      float gv[16];
#pragma unroll
      for (int j = 0; j < 16; ++j) {
        float z = v[j] + bias[gcol + j];
        float u = 0.7978845608028654f * (z + 0.044715f * z * z * z);
        gv[j] = z / (1.f + __expf(-2.f * u));
      }
      bf16* op = (bf16*)outp + (size_t)grow * HID + gcol;
      uint4 pk;
      pk.x = pack2(gv[0], gv[1]); pk.y = pack2(gv[2], gv[3]);
      pk.z = pack2(gv[4], gv[5]); pk.w = pack2(gv[6], gv[7]);
      *(uint4*)op = pk;
      pk.x = pack2(gv[8], gv[9]); pk.y = pack2(gv[10], gv[11]);
      pk.z = pack2(gv[12], gv[13]); pk.w = pack2(gv[14], gv[15]);
      *(uint4*)(op + 8) = pk;
    } else {
      float* op = (float*)outp + (size_t)grow * CDIM + gcol;
      const float* xr = extra + (size_t)grow * CDIM + gcol;
#pragma unroll
      for (int j = 0; j < 4; ++j) {
        float4 xv = *(const float4*)(xr + j * 4);
        float4 ov;
        ov.x = xv.x + v[j * 4 + 0] + bias[gcol + j * 4 + 0];
        ov.y = xv.y + v[j * 4 + 1] + bias[gcol + j * 4 + 1];
        ov.z = xv.z + v[j * 4 + 2] + bias[gcol + j * 4 + 2];
        ov.w = xv.w + v[j * 4 + 3] + bias[gcol + j * 4 + 3];
        *(float4*)(op + j * 4) = ov;
      }
    }
  }
}

// ============ attention on MFMA: 1 wave per (window, head) ==================
__global__ __launch_bounds__(64) void k_attn(const bf16* __restrict__ qkv,
                                             const float* __restrict__ tblg,
                                             bf16* __restrict__ out) {
  __shared__ __attribute__((aligned(16))) char pool[16384];
  bf16* Qs = (bf16*)pool;                                   // [64][40]
  bf16* Ks = (bf16*)(pool + 5120);                          // [64][40]
  bf16* Ps = (bf16*)pool;                                   // [64][72] alias
  float* Os = (float*)pool;                                 // [64][40] alias
  bf16* Vt = (bf16*)(pool + 10240);                         // [32][72]
  unsigned long long* msk = (unsigned long long*)(pool + 14848);  // [64]
  float* tbl = (float*)(pool + 15360);                      // [225]

  const int bid = blockIdx.x;
  const int win = bid / 12, head = bid - win * 12;
  const int lane = threadIdx.x;
  const int q = lane >> 4, mr = lane & 15;

  for (int i = lane; i < 225; i += 64) tbl[i] = tblg[i * 12 + head];

  size_t base = ((size_t)win * 12 + head) * 2048 + lane * 32;
  const uint4* qp = (const uint4*)(qkv + base);
  const uint4* kp = (const uint4*)(qkv + (size_t)12582912 + base);
  const uint4* vp = (const uint4*)(qkv + (size_t)25165824 + base);
#pragma unroll
  for (int i = 0; i < 4; ++i) *(uint4*)(Qs + lane * 40 + i * 8) = qp[i];
#pragma unroll
  for (int i = 0; i < 4; ++i) *(uint4*)(Ks + lane * 40 + i * 8) = kp[i];
  {
    union { uint4 u[4]; unsigned short h[32]; } vv;
#pragma unroll
    for (int i = 0; i < 4; ++i) vv.u[i] = vp[i];
    unsigned short* VtU = (unsigned short*)Vt;
#pragma unroll
    for (int d = 0; d < 32; ++d) VtU[d * 72 + lane] = vv.h[d];
  }
  {
    int wi = win & 15;
    int ri = lane >> 3, ci = lane & 7;
    int rh = ((wi >> 2) << 3) + ri, rw = ((wi & 3) << 3) + ci;
    int rid = (rh < 24 ? 0 : (rh < 28 ? 1 : 2)) * 3 + (rw < 24 ? 0 : (rw < 28 ? 1 : 2));
    unsigned long long m = 0;
#pragma unroll
    for (int v = 0; v < 9; ++v) {
      unsigned long long bb = __ballot(rid == v);
      if (rid == v) m = bb;
    }
    msk[lane] = m;
  }

  // ---- S = Q.K^T ----
  floatx4 sac[4][4];
#pragma unroll
  for (int i = 0; i < 4; ++i)
#pragma unroll
    for (int j = 0; j < 4; ++j) sac[i][j] = floatx4{0.f, 0.f, 0.f, 0.f};
  {
    short8 af[4], bf[4];
#pragma unroll
    for (int t = 0; t < 4; ++t) af[t] = *(const short8*)(Qs + (t * 16 + mr) * 40 + q * 8);
#pragma unroll
    for (int t = 0; t < 4; ++t) bf[t] = *(const short8*)(Ks + (t * 16 + mr) * 40 + q * 8);
#pragma unroll
    for (int mt = 0; mt < 4; ++mt)
#pragma unroll
      for (int nt = 0; nt < 4; ++nt)
        sac[mt][nt] = __builtin_amdgcn_mfma_f32_16x16x32_bf16(af[mt], bf[nt], sac[mt][nt], 0, 0, 0);
  }

  // ---- scale + bias + mask + exp; row sums; P -> LDS bf16 ----
  float psum[4][4];
#pragma unroll
  for (int mt = 0; mt < 4; ++mt)
#pragma unroll
    for (int r = 0; r < 4; ++r) psum[mt][r] = 0.f;
#pragma unroll
  for (int mt = 0; mt < 4; ++mt) {
#pragma unroll
    for (int r = 0; r < 4; ++r) {
      const int i = mt * 16 + q * 4 + r;
      const unsigned long long mrow = msk[i];
      const int bi = (i >> 3) * 15 + (i & 7);
#pragma unroll
      for (int nt = 0; nt < 4; ++nt) {
        const int j = nt * 16 + mr;
        const int idx = bi + 112 - (j >> 3) * 15 - (j & 7);
        float val = sac[mt][nt][r] * 0.17677669529663687f + tbl[idx];
        float p = __expf(val);
        p = ((mrow >> j) & 1ull) ? p : 0.f;
        psum[mt][r] += p;
        Ps[i * 72 + j] = f2bf(p);
      }
    }
  }
  float inv[4][4];
#pragma unroll
  for (int mt = 0; mt < 4; ++mt)
#pragma unroll
    for (int r = 0; r < 4; ++r) {
      float s = psum[mt][r];
      s += __shfl_xor(s, 1, 64);
      s += __shfl_xor(s, 2, 64);
      s += __shfl_xor(s, 4, 64);
      s += __shfl_xor(s, 8, 64);
      inv[mt][r] = 1.f / s;
    }

  // ---- O = P.V ----
  floatx4 oac[4][2];
#pragma unroll
  for (int i = 0; i < 4; ++i)
#pragma unroll
    for (int j = 0; j < 2; ++j) oac[i][j] = floatx4{0.f, 0.f, 0.f, 0.f};
#pragma unroll
  for (int kk = 0; kk < 2; ++kk) {
    short8 ap[4], bv[2];
#pragma unroll
    for (int mt = 0; mt < 4; ++mt)
      ap[mt] = *(const short8*)(Ps + (mt * 16 + mr) * 72 + kk * 32 + q * 8);
#pragma unroll
    for (int nt = 0; nt < 2; ++nt)
      bv[nt] = *(const short8*)(Vt + (nt * 16 + mr) * 72 + kk * 32 + q * 8);
#pragma unroll
    for (int mt = 0; mt < 4; ++mt)
#pragma unroll
      for (int nt = 0; nt < 2; ++nt)
        oac[mt][nt] = __builtin_amdgcn_mfma_f32_16x16x32_bf16(ap[mt], bv[nt], oac[mt][nt], 0, 0, 0);
  }

  // ---- normalize + LDS round-trip -> vectorized store ----
#pragma unroll
  for (int mt = 0; mt < 4; ++mt)
#pragma unroll
    for (int nt = 0; nt < 2; ++nt)
#pragma unroll
      for (int r = 0; r < 4; ++r)
        Os[(mt * 16 + q * 4 + r) * 40 + nt * 16 + mr] = oac[mt][nt][r] * inv[mt][r];
  float ov[32];
#pragma unroll
  for (int c = 0; c < 8; ++c) {
    const int cc = c ^ (lane & 7);
    float4 t = *(const float4*)(Os + lane * 40 + cc * 4);
    ov[cc * 4 + 0] = t.x; ov[cc * 4 + 1] = t.y;
    ov[cc * 4 + 2] = t.z; ov[cc * 4 + 3] = t.w;
  }
  uint4* o4 = (uint4*)(out + ((size_t)win * 64 + lane) * CDIM + head * 32);
#pragma unroll
  for (int i = 0; i < 4; ++i) {
    uint4 pk;
    pk.x = pack2(ov[i * 8 + 0], ov[i * 8 + 1]);
    pk.y = pack2(ov[i * 8 + 2], ov[i * 8 + 3]);
    pk.z = pack2(ov[i * 8 + 4], ov[i * 8 + 5]);
    pk.w = pack2(ov[i * 8 + 6], ov[i * 8 + 7]);
    o4[i] = pk;
  }
}

extern "C" void kernel_launch(void* const* d_in, const int* in_sizes, int n_in,
                              void* d_out, int out_size, void* d_ws, size_t ws_size,
                              hipStream_t stream) {
  const float* x = (const float*)d_in[0];
  const float* n1g = (const float*)d_in[1];
  const float* n1b = (const float*)d_in[2];
  const float* qkv_w = (const float*)d_in[3];
  const float* qkv_b = (const float*)d_in[4];
  const float* reltbl = (const float*)d_in[5];
  const float* proj_w = (const float*)d_in[6];
  const float* proj_b = (const float*)d_in[7];
  const float* n2g = (const float*)d_in[8];
  const float* n2b = (const float*)d_in[9];
  const float* fc1_w = (const float*)d_in[10];
  const float* fc1_b = (const float*)d_in[11];
  const float* fc2_w = (const float*)d_in[12];
  const float* fc2_b = (const float*)d_in[13];
  float* out = (float*)d_out;

  char* p = (char*)d_ws;
  bf16* w_qkv_t = (bf16*)p;  p += (size_t)442368 * 2;
  bf16* w_proj_t = (bf16*)p; p += (size_t)147456 * 2;
  bf16* w_fc1_t = (bf16*)p;  p += (size_t)589824 * 2;
  bf16* w_fc2_t = (bf16*)p;  p += (size_t)589824 * 2;
  bf16* bufA = (bf16*)p;     p += (size_t)12582912 * 2;
  bf16* qkvb = (bf16*)p;     p += (size_t)37748736 * 2;
  bf16* attno = (bf16*)p;    p += (size_t)12582912 * 2;
  float* x1 = (float*)p;     p += (size_t)12582912 * 4;
  bf16* hidden = qkvb;  // reuses dead qkv/attn regions

  k_convt<<<dim3((442368 + 255) / 256), dim3(256), 0, stream>>>(qkv_w, w_qkv_t, 384, 1152);
  k_convt<<<dim3((147456 + 255) / 256), dim3(256), 0, stream>>>(proj_w, w_proj_t, 384, 384);
  k_convt<<<dim3((589824 + 255) / 256), dim3(256), 0, stream>>>(fc1_w, w_fc1_t, 384, 1536);
  k_convt<<<dim3((589824 + 255) / 256), dim3(256), 0, stream>>>(fc2_w, w_fc2_t, 1536, 384);

  k_ln1<<<dim3(8192), dim3(256), 0, stream>>>(x, n1g, n1b, bufA);
  k_gemm<384, 0, 9, 128><<<dim3(9 * 256), dim3(256), 0, stream>>>(bufA, w_qkv_t, qkv_b, nullptr, qkvb);
  k_attn<<<dim3(6144), dim3(64), 0, stream>>>(qkvb, reltbl, attno);
  k_gemm<384, 1, 6, 64><<<dim3(6 * 256), dim3(256), 0, stream>>>(attno, w_proj_t, proj_b, x, x1);
  k_ln2<<<dim3(8192), dim3(256), 0, stream>>>(x1, n2g, n2b, bufA);
  k_gemm<384, 2, 12, 128><<<dim3(12 * 256), dim3(256), 0, stream>>>(bufA, w_fc1_t, fc1_b, nullptr, hidden);
  k_gemm<1536, 3, 6, 64><<<dim3(6 * 256), dim3(256), 0, stream>>>(hidden, w_fc2_t, fc2_b, x1, out);
}

// Round 8
// 455.778 us; speedup vs baseline: 2.0758x; 2.0758x over previous
//
#include <hip/hip_runtime.h>
#include <hip/hip_bf16.h>
#include <math.h>

typedef __hip_bfloat16 bf16;
typedef __attribute__((ext_vector_type(8))) short short8;
typedef __attribute__((ext_vector_type(4))) float floatx4;

static constexpr int TOK = 32768;
static constexpr int CDIM = 384;
static constexpr int HID = 1536;

__device__ __forceinline__ bf16 f2bf(float v) { return __float2bfloat16(v); }

__device__ __forceinline__ unsigned short bf_bits(float a) {
  bf16 h = __float2bfloat16(a);
  unsigned short u;
  __builtin_memcpy(&u, &h, 2);
  return u;
}
__device__ __forceinline__ unsigned pack2(float a, float b) {
  return (unsigned)bf_bits(a) | ((unsigned)bf_bits(b) << 16);
}

typedef const __attribute__((address_space(1))) unsigned gas_t;
typedef __attribute__((address_space(3))) unsigned las_t;
__device__ __forceinline__ void gload16(const bf16* g, const bf16* l) {
  __builtin_amdgcn_global_load_lds((gas_t*)g, (las_t*)l, 16, 0, 0);
}

// ---------------- weight fp32 -> bf16 transposed ----------------
__global__ void k_convt(const float* __restrict__ src, bf16* __restrict__ dst,
                        int Kd, int Nd) {
  int tid = blockIdx.x * 256 + threadIdx.x;
  if (tid >= Kd * Nd) return;
  int k = tid / Nd, n = tid - k * Nd;
  dst[(size_t)n * Kd + k] = f2bf(src[tid]);
}

// ---------------- LN1 + shift + window partition (4 tokens/block) -----------
__global__ __launch_bounds__(256) void k_ln1(const float* __restrict__ x,
                                             const float* __restrict__ g,
                                             const float* __restrict__ b,
                                             bf16* __restrict__ out) {
  int wt = blockIdx.x * 4 + (threadIdx.x >> 6);
  int lane = threadIdx.x & 63;
  int win = wt >> 6, ntok = wt & 63;
  int bimg = win >> 4, wi = win & 15;
  int sh = (((wi >> 2) << 3) + (ntok >> 3) + 4) & 31;
  int sw = (((wi & 3) << 3) + (ntok & 7) + 4) & 31;
  const float* xr = x + ((size_t)bimg * 1024 + sh * 32 + sw) * CDIM;
  float v[6]; float s = 0.f, ss = 0.f;
#pragma unroll
  for (int j = 0; j < 6; ++j) {
    float t = xr[j * 64 + lane];
    v[j] = t; s += t; ss += t * t;
  }
#pragma unroll
  for (int off = 32; off > 0; off >>= 1) {
    s += __shfl_xor(s, off, 64);
    ss += __shfl_xor(ss, off, 64);
  }
  float mu = s * (1.f / 384.f);
  float var = ss * (1.f / 384.f) - mu * mu;
  float rs = rsqrtf(var + 1e-5f);
  bf16* orow = out + (size_t)wt * CDIM;
#pragma unroll
  for (int j = 0; j < 6; ++j) {
    int c = j * 64 + lane;
    orow[c] = f2bf((v[j] - mu) * rs * g[c] + b[c]);
  }
}

// ---------------- LN2 (normal token order, 4 tokens/block) ------------------
__global__ __launch_bounds__(256) void k_ln2(const float* __restrict__ x1,
                                             const float* __restrict__ g,
                                             const float* __restrict__ b,
                                             bf16* __restrict__ out) {
  int t = blockIdx.x * 4 + (threadIdx.x >> 6);
  int lane = threadIdx.x & 63;
  const float* xr = x1 + (size_t)t * CDIM;
  float v[6]; float s = 0.f, ss = 0.f;
#pragma unroll
  for (int j = 0; j < 6; ++j) {
    float q = xr[j * 64 + lane];
    v[j] = q; s += q; ss += q * q;
  }
#pragma unroll
  for (int off = 32; off > 0; off >>= 1) {
    s += __shfl_xor(s, off, 64);
    ss += __shfl_xor(ss, off, 64);
  }
  float mu = s * (1.f / 384.f);
  float var = ss * (1.f / 384.f) - mu * mu;
  float rs = rsqrtf(var + 1e-5f);
  bf16* orow = out + (size_t)t * CDIM;
#pragma unroll
  for (int j = 0; j < 6; ++j) {
    int c = j * 64 + lane;
    orow[c] = f2bf((v[j] - mu) * rs * g[c] + b[c]);
  }
}

// ==== GEMM: TMx128 tile, BK=64, global_load_lds staging, XCD swizzle ========
// Staging via global_load_lds ONLY (R7's register-staged pipeline spilled
// accumulators to scratch: VGPR 48 + 837MB WRITE_SIZE — do not reintroduce).
// TM=128: 4 waves 2x2, 64x64 each (R6-verified). TM=256: 4 waves 2x2,
// 128x64 each (MT=8) — cuts LDS frag-read bytes/FLOP by 25% (LDS-BW-bound:
// R6 MfmaUtil 20% == 154cyc MFMA / 750cyc LDS per k-step).
// k-chunk XOR swizzle kept (R6 measured SQ_LDS_BANK_CONFLICT == 0).
template <int K, int EPI, int NT, int TM>
__global__ __launch_bounds__(256) void k_gemm(const bf16* __restrict__ A,
                                              const bf16* __restrict__ Bt,
                                              const float* __restrict__ bias,
                                              const float* __restrict__ extra,
                                              void* __restrict__ outp) {
  constexpr int MT = TM / 32;  // 16-row frags per wave (4 or 8)
  __shared__ __attribute__((aligned(16))) char pool[TM * 128 + 16384];
  bf16* As = (bf16*)pool;                  // [TM][64]
  bf16* Bs = (bf16*)(pool + TM * 128);     // [128][64]

  const int tid = threadIdx.x;
  const int wv = tid >> 6, lane = tid & 63;

  const int flat = blockIdx.x;
  const int xcd = flat & 7;
  const int idx = flat >> 3;
  const int rpx = (gridDim.x >> 3) / NT;
  const int cb = idx % NT;
  const int rb = idx / NT;
  const int mblk = (xcd * rpx + rb) * TM, nblk = cb * 128;

  const int srow = lane >> 3;
  const int scol8 = (lane & 7) ^ srow;
  const bf16* gaw = A + (size_t)(mblk + wv * (TM / 4) + srow) * K + scol8 * 8;
  const bf16* gbw = Bt + (size_t)(nblk + wv * 32 + srow) * K + scol8 * 8;
  const bf16* lAw = As + wv * (TM / 4) * 64;
  const bf16* lBw = Bs + wv * 2048;

  const int wr = wv >> 1, wc = wv & 1;
  const int mr = lane & 15, q = lane >> 4;
  const bf16* faRow = As + (wr * (TM / 2) + mr) * 64;
  const bf16* fbRow = Bs + (wc * 64 + mr) * 64;
  const int sw0 = (q ^ (mr & 7)) * 8;
  const int sw4 = ((q + 4) ^ (mr & 7)) * 8;

  floatx4 acc[MT][4];
#pragma unroll
  for (int i = 0; i < MT; ++i)
#pragma unroll
    for (int j = 0; j < 4; ++j) acc[i][j] = floatx4{0.f, 0.f, 0.f, 0.f};

  for (int k0 = 0; k0 < K; k0 += 64) {
    __syncthreads();
#pragma unroll
    for (int c = 0; c < MT; ++c) gload16(gaw + k0 + c * 8 * K, lAw + c * 512);
#pragma unroll
    for (int c = 0; c < 4; ++c) gload16(gbw + k0 + c * 8 * K, lBw + c * 512);
    __syncthreads();
#pragma unroll
    for (int half = 0; half < 2; ++half) {
      const int sw = half ? sw4 : sw0;
      short8 b[4];
#pragma unroll
      for (int nt = 0; nt < 4; ++nt) b[nt] = *(const short8*)(fbRow + nt * 1024 + sw);
#pragma unroll
      for (int mt = 0; mt < MT; ++mt) {
        short8 a = *(const short8*)(faRow + mt * 1024 + sw);
#pragma unroll
        for (int nt = 0; nt < 4; ++nt)
          acc[mt][nt] = __builtin_amdgcn_mfma_f32_16x16x32_bf16(a, b[nt], acc[mt][nt], 0, 0, 0);
      }
    }
  }

  // epilogue: staging LDS dead -> alias per-wave transpose buffers
  // (FULLY UNROLLED — runtime-indexed acc[] spills to scratch, see R2/R7)
  __syncthreads();
  float* epsw = (float*)pool + wv * (16 * 68);
  const int rr = lane >> 2, c0 = (lane & 3) * 16;
#pragma unroll
  for (int mt = 0; mt < MT; ++mt) {
#pragma unroll
    for (int nt = 0; nt < 4; ++nt)
#pragma unroll
      for (int r = 0; r < 4; ++r)
        epsw[(q * 4 + r) * 68 + nt * 16 + mr] = acc[mt][nt][r];
    float v[16];
#pragma unroll
    for (int j = 0; j < 4; ++j) {
      float4 t = *(const float4*)&epsw[rr * 68 + c0 + j * 4];
      v[j * 4 + 0] = t.x; v[j * 4 + 1] = t.y; v[j * 4 + 2] = t.z; v[j * 4 + 3] = t.w;
    }
    const int grow = mblk + wr * (TM / 2) + mt * 16 + rr;
    const int gcol = nblk + wc * 64 + c0;

    if constexpr (EPI == 0) {
      int win = grow >> 6, ntok = grow & 63;
      int s = gcol / 384;
      int rem = gcol - s * 384;
      int h = rem >> 5, d0 = rem & 31;
      bf16* op = (bf16*)outp + (((size_t)s * 512 + win) * 12 + h) * 2048 + ntok * 32 + d0;
      uint4 pk;
      float bv[16];
#pragma unroll
      for (int j = 0; j < 16; ++j) bv[j] = v[j] + bias[gcol + j];
      pk.x = pack2(bv[0], bv[1]); pk.y = pack2(bv[2], bv[3]);
      pk.z = pack2(bv[4], bv[5]); pk.w = pack2(bv[6], bv[7]);
      *(uint4*)op = pk;
      pk.x = pack2(bv[8], bv[9]); pk.y = pack2(bv[10], bv[11]);
      pk.z = pack2(bv[12], bv[13]); pk.w = pack2(bv[14], bv[15]);
      *(uint4*)(op + 8) = pk;
    } else if constexpr (EPI == 1) {
      int win = grow >> 6, ntok = grow & 63;
      int bimg = win >> 4, wi = win & 15;
      int hh = (((wi >> 2) << 3) + (ntok >> 3) + 4) & 31;
      int ww = (((wi & 3) << 3) + (ntok & 7) + 4) & 31;
      size_t t = (size_t)bimg * 1024 + hh * 32 + ww;
      float* op = (float*)outp + t * CDIM + gcol;
      const float* xr = extra + t * CDIM + gcol;
#pragma unroll
      for (int j = 0; j < 4; ++j) {
        float4 xv = *(const float4*)(xr + j * 4);
        float4 ov;
        ov.x = xv.x + v[j * 4 + 0] + bias[gcol + j * 4 + 0];
        ov.y = xv.y + v[j * 4 + 1] + bias[gcol + j * 4 + 1];
        ov.z = xv.z + v[j * 4 + 2] + bias[gcol + j * 4 + 2];
        ov.w = xv.w + v[j * 4 + 3] + bias[gcol + j * 4 + 3];
        *(float4*)(op + j * 4) = ov;
      }
    } else if constexpr (EPI == 2) {
      float gv[16];
#pragma unroll
      for (int j = 0; j < 16; ++j) {
        float z = v[j] + bias[gcol + j];
        float u = 0.7978845608028654f * (z + 0.044715f * z * z * z);
        gv[j] = z / (1.f + __expf(-2.f * u));
      }
      bf16* op = (bf16*)outp + (size_t)grow * HID + gcol;
      uint4 pk;
      pk.x = pack2(gv[0], gv[1]); pk.y = pack2(gv[2], gv[3]);
      pk.z = pack2(gv[4], gv[5]); pk.w = pack2(gv[6], gv[7]);
      *(uint4*)op = pk;
      pk.x = pack2(gv[8], gv[9]); pk.y = pack2(gv[10], gv[11]);
      pk.z = pack2(gv[12], gv[13]); pk.w = pack2(gv[14], gv[15]);
      *(uint4*)(op + 8) = pk;
    } else {
      float* op = (float*)outp + (size_t)grow * CDIM + gcol;
      const float* xr = extra + (size_t)grow * CDIM + gcol;
#pragma unroll
      for (int j = 0; j < 4; ++j) {
        float4 xv = *(const float4*)(xr + j * 4);
        float4 ov;
        ov.x = xv.x + v[j * 4 + 0] + bias[gcol + j * 4 + 0];
        ov.y = xv.y + v[j * 4 + 1] + bias[gcol + j * 4 + 1];
        ov.z = xv.z + v[j * 4 + 2] + bias[gcol + j * 4 + 2];
        ov.w = xv.w + v[j * 4 + 3] + bias[gcol + j * 4 + 3];
        *(float4*)(op + j * 4) = ov;
      }
    }
  }
}

// ============ attention on MFMA: 1 wave per (window, head) ==================
__global__ __launch_bounds__(64) void k_attn(const bf16* __restrict__ qkv,
                                             const float* __restrict__ tblg,
                                             bf16* __restrict__ out) {
  __shared__ __attribute__((aligned(16))) char pool[16384];
  bf16* Qs = (bf16*)pool;                                   // [64][40]
  bf16* Ks = (bf16*)(pool + 5120);                          // [64][40]
  bf16* Ps = (bf16*)pool;                                   // [64][72] alias
  float* Os = (float*)pool;                                 // [64][40] alias
  bf16* Vt = (bf16*)(pool + 10240);                         // [32][72]
  unsigned long long* msk = (unsigned long long*)(pool + 14848);  // [64]
  float* tbl = (float*)(pool + 15360);                      // [225]

  const int bid = blockIdx.x;
  const int win = bid / 12, head = bid - win * 12;
  const int lane = threadIdx.x;
  const int q = lane >> 4, mr = lane & 15;

  for (int i = lane; i < 225; i += 64) tbl[i] = tblg[i * 12 + head];

  size_t base = ((size_t)win * 12 + head) * 2048 + lane * 32;
  const uint4* qp = (const uint4*)(qkv + base);
  const uint4* kp = (const uint4*)(qkv + (size_t)12582912 + base);
  const uint4* vp = (const uint4*)(qkv + (size_t)25165824 + base);
#pragma unroll
  for (int i = 0; i < 4; ++i) *(uint4*)(Qs + lane * 40 + i * 8) = qp[i];
#pragma unroll
  for (int i = 0; i < 4; ++i) *(uint4*)(Ks + lane * 40 + i * 8) = kp[i];
  {
    union { uint4 u[4]; unsigned short h[32]; } vv;
#pragma unroll
    for (int i = 0; i < 4; ++i) vv.u[i] = vp[i];
    unsigned short* VtU = (unsigned short*)Vt;
#pragma unroll
    for (int d = 0; d < 32; ++d) VtU[d * 72 + lane] = vv.h[d];
  }
  {
    int wi = win & 15;
    int ri = lane >> 3, ci = lane & 7;
    int rh = ((wi >> 2) << 3) + ri, rw = ((wi & 3) << 3) + ci;
    int rid = (rh < 24 ? 0 : (rh < 28 ? 1 : 2)) * 3 + (rw < 24 ? 0 : (rw < 28 ? 1 : 2));
    unsigned long long m = 0;
#pragma unroll
    for (int v = 0; v < 9; ++v) {
      unsigned long long bb = __ballot(rid == v);
      if (rid == v) m = bb;
    }
    msk[lane] = m;
  }

  // ---- S = Q.K^T ----
  floatx4 sac[4][4];
#pragma unroll
  for (int i = 0; i < 4; ++i)
#pragma unroll
    for (int j = 0; j < 4; ++j) sac[i][j] = floatx4{0.f, 0.f, 0.f, 0.f};
  {
    short8 af[4], bf[4];
#pragma unroll
    for (int t = 0; t < 4; ++t) af[t] = *(const short8*)(Qs + (t * 16 + mr) * 40 + q * 8);
#pragma unroll
    for (int t = 0; t < 4; ++t) bf[t] = *(const short8*)(Ks + (t * 16 + mr) * 40 + q * 8);
#pragma unroll
    for (int mt = 0; mt < 4; ++mt)
#pragma unroll
      for (int nt = 0; nt < 4; ++nt)
        sac[mt][nt] = __builtin_amdgcn_mfma_f32_16x16x32_bf16(af[mt], bf[nt], sac[mt][nt], 0, 0, 0);
  }

  // ---- scale + bias + mask + exp; row sums; P -> LDS bf16 ----
  float psum[4][4];
#pragma unroll
  for (int mt = 0; mt < 4; ++mt)
#pragma unroll
    for (int r = 0; r < 4; ++r) psum[mt][r] = 0.f;
#pragma unroll
  for (int mt = 0; mt < 4; ++mt) {
#pragma unroll
    for (int r = 0; r < 4; ++r) {
      const int i = mt * 16 + q * 4 + r;
      const unsigned long long mrow = msk[i];
      const int bi = (i >> 3) * 15 + (i & 7);
#pragma unroll
      for (int nt = 0; nt < 4; ++nt) {
        const int j = nt * 16 + mr;
        const int idx = bi + 112 - (j >> 3) * 15 - (j & 7);
        float val = sac[mt][nt][r] * 0.17677669529663687f + tbl[idx];
        float p = __expf(val);
        p = ((mrow >> j) & 1ull) ? p : 0.f;
        psum[mt][r] += p;
        Ps[i * 72 + j] = f2bf(p);
      }
    }
  }
  float inv[4][4];
#pragma unroll
  for (int mt = 0; mt < 4; ++mt)
#pragma unroll
    for (int r = 0; r < 4; ++r) {
      float s = psum[mt][r];
      s += __shfl_xor(s, 1, 64);
      s += __shfl_xor(s, 2, 64);
      s += __shfl_xor(s, 4, 64);
      s += __shfl_xor(s, 8, 64);
      inv[mt][r] = 1.f / s;
    }

  // ---- O = P.V ----
  floatx4 oac[4][2];
#pragma unroll
  for (int i = 0; i < 4; ++i)
#pragma unroll
    for (int j = 0; j < 2; ++j) oac[i][j] = floatx4{0.f, 0.f, 0.f, 0.f};
#pragma unroll
  for (int kk = 0; kk < 2; ++kk) {
    short8 ap[4], bv[2];
#pragma unroll
    for (int mt = 0; mt < 4; ++mt)
      ap[mt] = *(const short8*)(Ps + (mt * 16 + mr) * 72 + kk * 32 + q * 8);
#pragma unroll
    for (int nt = 0; nt < 2; ++nt)
      bv[nt] = *(const short8*)(Vt + (nt * 16 + mr) * 72 + kk * 32 + q * 8);
#pragma unroll
    for (int mt = 0; mt < 4; ++mt)
#pragma unroll
      for (int nt = 0; nt < 2; ++nt)
        oac[mt][nt] = __builtin_amdgcn_mfma_f32_16x16x32_bf16(ap[mt], bv[nt], oac[mt][nt], 0, 0, 0);
  }

  // ---- normalize + LDS round-trip -> vectorized store ----
#pragma unroll
  for (int mt = 0; mt < 4; ++mt)
#pragma unroll
    for (int nt = 0; nt < 2; ++nt)
#pragma unroll
      for (int r = 0; r < 4; ++r)
        Os[(mt * 16 + q * 4 + r) * 40 + nt * 16 + mr] = oac[mt][nt][r] * inv[mt][r];
  float ov[32];
#pragma unroll
  for (int c = 0; c < 8; ++c) {
    const int cc = c ^ (lane & 7);
    float4 t = *(const float4*)(Os + lane * 40 + cc * 4);
    ov[cc * 4 + 0] = t.x; ov[cc * 4 + 1] = t.y;
    ov[cc * 4 + 2] = t.z; ov[cc * 4 + 3] = t.w;
  }
  uint4* o4 = (uint4*)(out + ((size_t)win * 64 + lane) * CDIM + head * 32);
#pragma unroll
  for (int i = 0; i < 4; ++i) {
    uint4 pk;
    pk.x = pack2(ov[i * 8 + 0], ov[i * 8 + 1]);
    pk.y = pack2(ov[i * 8 + 2], ov[i * 8 + 3]);
    pk.z = pack2(ov[i * 8 + 4], ov[i * 8 + 5]);
    pk.w = pack2(ov[i * 8 + 6], ov[i * 8 + 7]);
    o4[i] = pk;
  }
}

extern "C" void kernel_launch(void* const* d_in, const int* in_sizes, int n_in,
                              void* d_out, int out_size, void* d_ws, size_t ws_size,
                              hipStream_t stream) {
  const float* x = (const float*)d_in[0];
  const float* n1g = (const float*)d_in[1];
  const float* n1b = (const float*)d_in[2];
  const float* qkv_w = (const float*)d_in[3];
  const float* qkv_b = (const float*)d_in[4];
  const float* reltbl = (const float*)d_in[5];
  const float* proj_w = (const float*)d_in[6];
  const float* proj_b = (const float*)d_in[7];
  const float* n2g = (const float*)d_in[8];
  const float* n2b = (const float*)d_in[9];
  const float* fc1_w = (const float*)d_in[10];
  const float* fc1_b = (const float*)d_in[11];
  const float* fc2_w = (const float*)d_in[12];
  const float* fc2_b = (const float*)d_in[13];
  float* out = (float*)d_out;

  char* p = (char*)d_ws;
  bf16* w_qkv_t = (bf16*)p;  p += (size_t)442368 * 2;
  bf16* w_proj_t = (bf16*)p; p += (size_t)147456 * 2;
  bf16* w_fc1_t = (bf16*)p;  p += (size_t)589824 * 2;
  bf16* w_fc2_t = (bf16*)p;  p += (size_t)589824 * 2;
  bf16* bufA = (bf16*)p;     p += (size_t)12582912 * 2;
  bf16* qkvb = (bf16*)p;     p += (size_t)37748736 * 2;
  bf16* attno = (bf16*)p;    p += (size_t)12582912 * 2;
  float* x1 = (float*)p;     p += (size_t)12582912 * 4;
  bf16* hidden = qkvb;  // reuses dead qkv/attn regions

  k_convt<<<dim3((442368 + 255) / 256), dim3(256), 0, stream>>>(qkv_w, w_qkv_t, 384, 1152);
  k_convt<<<dim3((147456 + 255) / 256), dim3(256), 0, stream>>>(proj_w, w_proj_t, 384, 384);
  k_convt<<<dim3((589824 + 255) / 256), dim3(256), 0, stream>>>(fc1_w, w_fc1_t, 384, 1536);
  k_convt<<<dim3((589824 + 255) / 256), dim3(256), 0, stream>>>(fc2_w, w_fc2_t, 1536, 384);

  k_ln1<<<dim3(8192), dim3(256), 0, stream>>>(x, n1g, n1b, bufA);
  k_gemm<384, 0, 9, 256><<<dim3(9 * 128), dim3(256), 0, stream>>>(bufA, w_qkv_t, qkv_b, nullptr, qkvb);
  k_attn<<<dim3(6144), dim3(64), 0, stream>>>(qkvb, reltbl, attno);
  k_gemm<384, 1, 3, 128><<<dim3(3 * 256), dim3(256), 0, stream>>>(attno, w_proj_t, proj_b, x, x1);
  k_ln2<<<dim3(8192), dim3(256), 0, stream>>>(x1, n2g, n2b, bufA);
  k_gemm<384, 2, 12, 256><<<dim3(12 * 128), dim3(256), 0, stream>>>(bufA, w_fc1_t, fc1_b, nullptr, hidden);
  k_gemm<1536, 3, 3, 128><<<dim3(3 * 256), dim3(256), 0, stream>>>(hidden, w_fc2_t, fc2_b, x1, out);
}